// Round 1
// baseline (555.165 us; speedup 1.0000x reference)
//
#include <hip/hip_runtime.h>
#include <cstddef>

#define T_LEN 512
#define IN_D 8
#define H 32
#define NBATCH 16        // batches per WG (MFMA M)
#define NT 256           // 4 waves: wave w owns gate w (0=i,1=f,2=g,3=o)
#define LOG2E 1.44269504088896341f
#define GP 44            // G row pad (words): 44cc+8q -> <=2-way banks

typedef __attribute__((ext_vector_type(8))) short bf16x8;
typedef __attribute__((ext_vector_type(4))) float f32x4;
typedef __attribute__((ext_vector_type(2))) float f32x2;
typedef __attribute__((ext_vector_type(4))) unsigned u32x4;

__device__ __forceinline__ float fexp2(float v) { return __builtin_amdgcn_exp2f(v); }
__device__ __forceinline__ float frcp(float v)  { return __builtin_amdgcn_rcpf(v); }
__device__ __forceinline__ unsigned short f2bf(float f) {   // RNE fp32->bf16 (setup only)
    unsigned u = __builtin_bit_cast(unsigned, f);
    u += 0x7FFF + ((u >> 16) & 1);
    return (unsigned short)(u >> 16);
}
__device__ __forceinline__ float bf2f(unsigned short b) {
    unsigned u = ((unsigned)b) << 16;
    return __builtin_bit_cast(float, u);
}
__device__ __forceinline__ float ubits(unsigned u) { return __builtin_bit_cast(float, u); }
// packed RNE fp32x2 -> bf16x2 (lo -> low16, hi -> high16)
__device__ __forceinline__ unsigned cvt_pk_bf16(float lo, float hi) {
    unsigned r;
    asm("v_cvt_pk_bf16_f32 %0, %1, %2" : "=v"(r) : "v"(lo), "v"(hi));
    return r;
}

// LDS-only barrier: no vmcnt drain (global x-chunk loads stay in flight).
#define WG_BARRIER() asm volatile("s_waitcnt lgkmcnt(0)\n\ts_barrier" ::: "memory")

// One barrier per step. Wave w computes gate w (8 MFMAs: 3 h-part + 1 K-packed
// x-part per tile, x hi/lo/hi folded into one K=32 MFMA). Activated gates go to
// ping-pong G[2][4][16][44] (b64 writes, b128 reads, pad-44). After the barrier
// EVERY wave redundantly runs the c/h update for exactly the 8 cells its own
// A-fragment needs (batch=cc, k=8q+j) -> h stays in registers, no 2nd barrier,
// no h LDS round-trip. kk (+/-log2e) premultiplied into B-frags/bias; g-gate
// stored as 2*log2e*tanh(g) so c recurrence runs in exp2 domain.
__global__ void __launch_bounds__(NT, 2) lstm_mfma4(
    const float* __restrict__ x, const float* __restrict__ W_ih,
    const float* __restrict__ W_hh, const float* __restrict__ b_ih,
    const float* __restrict__ b_hh, const float* __restrict__ W_fc,
    const float* __restrict__ b_fc, float* __restrict__ out)
{
    __shared__ __align__(16) float G[2][4][NBATCH][GP];            // 22528 B
    __shared__ __align__(16) unsigned short xpk[2][8][NBATCH][24]; // 12288 B; k0-7=xh,8-15=xl,16-23=0

    const int tix  = threadIdx.x;
    const int w    = tix >> 6;          // gate id
    const int lane = tix & 63;
    const int q    = lane >> 4;         // k-quad (A/B) / row-group (C)
    const int cc   = lane & 15;         // A row (batch) / B col (unit-in-tile)

    const float kk = (w == 2) ? 2.f * LOG2E : -LOG2E;
    const float aa = (w == 2) ? 2.f * LOG2E : 0.f;     // g stored as 2L*tanh
    const float bb = (w == 2) ? -4.f * LOG2E : 1.f;

    // ---- static B fragments for gate w (premultiplied by kk) ----
    bf16x8 Bh[2], Bl[2], Bx[2];
    float bias[2];
    #pragma unroll
    for (int d = 0; d < 2; ++d) {
        const int r = 16 * (2 * w + d) + cc;          // global gate-row
        #pragma unroll
        for (int j = 0; j < 8; ++j) {
            const int p = 8 * q + j;                  // k position (pi-order)
            const int u = 16 * (p & 1) + (p >> 1);    // unit index
            const float ws = kk * W_hh[r * H + u];
            const unsigned short whi = f2bf(ws);
            Bh[d][j] = (short)whi;
            Bl[d][j] = (short)f2bf(ws - bf2f(whi));
            if (q == 3) {
                Bx[d][j] = 0;                          // zero k-quad
            } else {
                const float wsx = kk * W_ih[r * IN_D + j];
                const unsigned short xwh = f2bf(wsx);
                // q=0,1 multiply x_hi/x_lo by W_hi; q=2 multiplies x_hi by W_lo
                Bx[d][j] = (q == 2) ? (short)f2bf(wsx - bf2f(xwh)) : (short)xwh;
            }
        }
        bias[d] = kk * (b_ih[r] + b_hh[r]);
    }

    // per-lane x A-frag offset: q0->xh, q1->xl, q2->xh (again), q3->zeros
    const int xoff = (q == 2) ? 0 : ((q == 3) ? 16 : 8 * q);

    // ---- x chunk machinery: thread -> (batch xb, step-in-chunk xs, half xhf) ----
    const int xb = tix >> 4, xs = (tix >> 1) & 7, xhf = tix & 1;
    const float* xbase = x + (size_t)(blockIdx.x * NBATCH + xb) * (size_t)(T_LEN * IN_D)
                           + xs * IN_D + 4 * xhf;
    auto ldchunk = [&](int ch) { return *(const float4*)(xbase + (size_t)ch * 8 * IN_D); };
    auto stage = [&](unsigned short (*xn)[NBATCH][24], float4 v) {
        const unsigned h0 = cvt_pk_bf16(v.x, v.y);
        const unsigned h1 = cvt_pk_bf16(v.z, v.w);
        const unsigned l0 = cvt_pk_bf16(v.x - ubits(h0 << 16), v.y - ubits(h0 & 0xffff0000u));
        const unsigned l1 = cvt_pk_bf16(v.z - ubits(h1 << 16), v.w - ubits(h1 & 0xffff0000u));
        *(uint2*)&xn[xs][xb][4 * xhf]     = make_uint2(h0, h1);
        *(uint2*)&xn[xs][xb][8 + 4 * xhf] = make_uint2(l0, l1);
    };

    // ---- init: zero xpk (persistent zero region), stage chunk 0, chunk 1 in flight ----
    for (int i = tix; i < (int)(sizeof(xpk) / 4); i += NT) ((unsigned*)xpk)[i] = 0u;
    __syncthreads();                    // zero-fill visible before staging overwrites
    stage(xpk[0], ldchunk(0));
    float4 xbuf = ldchunk(1);

    float wfc[8];
    #pragma unroll
    for (int j = 0; j < 8; ++j) {
        const int p = 8 * q + j;
        wfc[j] = W_fc[16 * (p & 1) + (p >> 1)];
    }

    u32x4 A0w = {0u, 0u, 0u, 0u}, A2w = {0u, 0u, 0u, 0u};   // h hi / h lo frags
    float cs[8], hh[8];
    #pragma unroll
    for (int j = 0; j < 8; ++j) { cs[j] = 0.f; hh[j] = 0.f; }

    __syncthreads();                    // once; full drain acceptable outside loop

    int cur = 0;
    for (int blk = 0; blk < T_LEN / 8; ++blk) {
        const unsigned short (*xc)[NBATCH][24] = xpk[cur];
        unsigned short (*xn)[NBATCH][24] = xpk[cur ^ 1];
        #pragma unroll
        for (int s = 0; s < 8; ++s) {
            const int par = s & 1;      // G ping-pong parity (compile-time)

            // ---- 8 MFMAs: per tile, 2 chains of 2 ----
            const bf16x8 A0 = __builtin_bit_cast(bf16x8, A0w);
            const bf16x8 A2 = __builtin_bit_cast(bf16x8, A2w);
            const bf16x8 Ax = *(const bf16x8*)&xc[s][cc][xoff];
            f32x4 C2[2];
            #pragma unroll
            for (int d = 0; d < 2; ++d) {
                f32x4 a1 = { bias[d], bias[d], bias[d], bias[d] };
                f32x4 a2 = { 0.f, 0.f, 0.f, 0.f };
                a1 = __builtin_amdgcn_mfma_f32_16x16x32_bf16(A0, Bh[d], a1, 0, 0, 0);
                a2 = __builtin_amdgcn_mfma_f32_16x16x32_bf16(Ax, Bx[d], a2, 0, 0, 0);
                a1 = __builtin_amdgcn_mfma_f32_16x16x32_bf16(A2, Bh[d], a1, 0, 0, 0);
                a2 = __builtin_amdgcn_mfma_f32_16x16x32_bf16(A0, Bl[d], a2, 0, 0, 0);
                C2[d] = a1 + a2;
            }

            // ---- activation (kk pre-folded) -> b64 G writes (d-pair adjacent) ----
            #pragma unroll
            for (int rg = 0; rg < 4; ++rg) {
                const float g0 = aa + bb * frcp(1.f + fexp2(C2[0][rg]));
                const float g1 = aa + bb * frcp(1.f + fexp2(C2[1][rg]));
                f32x2 pr = { g0, g1 };
                *(f32x2*)&G[par][w][4 * q + rg][2 * cc] = pr;   // p = 2cc+d
            }

            // ---- chunk boundary: stage next 8 steps, refill pipeline ----
            if (s == 7) {
                stage(xn, xbuf);
                int nc = blk + 2;
                if (nc > T_LEN / 8 - 1) nc = T_LEN / 8 - 1;
                xbuf = ldchunk(nc);
            }

            WG_BARRIER();               // the ONLY barrier per step

            // ---- redundant c/h update: exactly this lane's A-frag cells ----
            f32x4 Gv[4][2];
            #pragma unroll
            for (int g = 0; g < 4; ++g) {
                Gv[g][0] = *(const f32x4*)&G[par][g][cc][8 * q];
                Gv[g][1] = *(const f32x4*)&G[par][g][cc][8 * q + 4];
            }
            #pragma unroll
            for (int j = 0; j < 8; ++j) {
                const int vh = j >> 2, vl = j & 3;
                const float iv = Gv[0][vh][vl];
                const float fv = Gv[1][vh][vl];
                const float gv = Gv[2][vh][vl];   // already 2L*tanh(g)
                const float ov = Gv[3][vh][vl];
                cs[j] = fv * cs[j] + iv * gv;     // cs = 2L*c
                const float e = fexp2(cs[j]);     // e^{2c}
                const float r = frcp(1.f + e);
                hh[j] = ov - 2.f * ov * r;        // o * tanh(c)
            }
            // ---- pack h -> bf16 hi/lo A-frags in-register ----
            #pragma unroll
            for (int jp = 0; jp < 4; ++jp) {
                const unsigned hw = cvt_pk_bf16(hh[2 * jp], hh[2 * jp + 1]);
                const unsigned lw = cvt_pk_bf16(hh[2 * jp]     - ubits(hw << 16),
                                                hh[2 * jp + 1] - ubits(hw & 0xffff0000u));
                A0w[jp] = hw;
                A2w[jp] = lw;
            }
        }
        cur ^= 1;
    }

    // ---- epilogue: out[b] = h_n . W_fc + b_fc (fp32 h, shfl reduce over q) ----
    float sacc = 0.f;
    #pragma unroll
    for (int j = 0; j < 8; ++j) sacc += hh[j] * wfc[j];
    sacc += __shfl_xor(sacc, 16);
    sacc += __shfl_xor(sacc, 32);
    if (tix < NBATCH) out[blockIdx.x * NBATCH + tix] = sacc + b_fc[0];
}

extern "C" void kernel_launch(void* const* d_in, const int* in_sizes, int n_in,
                              void* d_out, int out_size, void* d_ws, size_t ws_size,
                              hipStream_t stream) {
    const float* x    = (const float*)d_in[0];
    const float* W_ih = (const float*)d_in[1];
    const float* W_hh = (const float*)d_in[2];
    const float* b_ih = (const float*)d_in[3];
    const float* b_hh = (const float*)d_in[4];
    const float* W_fc = (const float*)d_in[5];
    const float* b_fc = (const float*)d_in[6];
    float* out = (float*)d_out;
    const int Bn = in_sizes[0] / (T_LEN * IN_D);   // 8192
    lstm_mfma4<<<dim3(Bn / NBATCH), dim3(NT), 0, stream>>>(
        x, W_ih, W_hh, b_ih, b_hh, W_fc, b_fc, out);
}

// Round 2
// 474.445 us; speedup vs baseline: 1.1701x; 1.1701x over previous
//
#include <hip/hip_runtime.h>
#include <cstddef>

#define T_LEN 512
#define IN_D 8
#define H 32
#define NBATCH 16        // batches per WG (MFMA M)
#define NT 256           // 4 waves: wave w owns gate w (0=i,1=f,2=g,3=o)
#define NCHUNK (T_LEN / 8)
#define LOG2E 1.44269504088896341f

typedef __attribute__((ext_vector_type(8))) short bf16x8;
typedef __attribute__((ext_vector_type(4))) float f32x4;
typedef __attribute__((ext_vector_type(2))) float f32x2;

__device__ __forceinline__ float fexp2(float v) { return __builtin_amdgcn_exp2f(v); }
__device__ __forceinline__ float frcp(float v)  { return __builtin_amdgcn_rcpf(v); }
__device__ __forceinline__ unsigned short f2bf(float f) {   // RNE fp32->bf16 (setup only)
    unsigned u = __builtin_bit_cast(unsigned, f);
    u += 0x7FFF + ((u >> 16) & 1);
    return (unsigned short)(u >> 16);
}
__device__ __forceinline__ float bf2f(unsigned short b) {
    unsigned u = ((unsigned)b) << 16;
    return __builtin_bit_cast(float, u);
}
__device__ __forceinline__ float ubits(unsigned u) { return __builtin_bit_cast(float, u); }
// packed RNE fp32x2 -> bf16x2 (arg0 -> low16, arg1 -> high16)
__device__ __forceinline__ unsigned cvt_pk_bf16(float lo, float hi) {
    unsigned r;
    asm("v_cvt_pk_bf16_f32 %0, %1, %2" : "=v"(r) : "v"(lo), "v"(hi));
    return r;
}

// LDS-only barrier: no vmcnt drain (global x-chunk loads stay in flight).
#define WG_BARRIER() asm volatile("s_waitcnt lgkmcnt(0)\n\ts_barrier" ::: "memory")

// r0 structure (two barriers, non-redundant c/h update: r1's redundant-TRANS
// experiment cost more than the barrier it saved) + x-contribution hoisted out
// of the recurrence entirely: XC[s][d] = bias + x.(kk*W_ih)^T precomputed one
// K-packed MFMA per (s,d) into 64 VGPRs, refilled 2 MFMAs/step spread across
// the chunk. Per-step recurrence: 2 b128 A-reads + 6 MFMAs + activation ->
// G[4][16][40] (pi-paired, b64 writes/reads at the 128-word bank minimum) ->
// barrier -> c/h (2 cells/thread, exp2-domain c) -> cvt_pk h hi/lo -> barrier.
// h arrays pitch 48: h-writes even 2-way, A-frag b128 reads even 8/bank.
__global__ void __launch_bounds__(NT, 1) lstm_mfma4(
    const float* __restrict__ x, const float* __restrict__ W_ih,
    const float* __restrict__ W_hh, const float* __restrict__ b_ih,
    const float* __restrict__ b_hh, const float* __restrict__ W_fc,
    const float* __restrict__ b_fc, float* __restrict__ out)
{
    __shared__ __align__(16) float G[4][NBATCH][40];           // 10240 B, col p=2cc+d (pi pairs)
    __shared__ __align__(16) unsigned short hhi[NBATCH][48];   // 1536 B, pi-order k
    __shared__ __align__(16) unsigned short hlo[NBATCH][48];   // 1536 B
    __shared__ __align__(16) unsigned short xstg[8][17][24];   // 6528 B; [17] breaks xs-stride bank alias

    const int tix  = threadIdx.x;
    const int w    = tix >> 6;          // gate id
    const int lane = tix & 63;
    const int q    = lane >> 4;         // k-quad (A/B) / row-group (C)
    const int cc   = lane & 15;         // A row (batch) / B col (unit-in-tile)

    const float kk = (w == 2) ? 2.f * LOG2E : -LOG2E;
    const float aa = (w == 2) ? 2.f * LOG2E : 0.f;     // g stored as 2L*tanh(g)
    const float bb = (w == 2) ? -4.f * LOG2E : 1.f;

    // ---- static B fragments for gate w (premultiplied by kk) ----
    bf16x8 Bh[2], Bl[2], Bx[2];
    float bias[2];
    #pragma unroll
    for (int d = 0; d < 2; ++d) {
        const int r = 16 * (2 * w + d) + cc;          // global gate-row
        #pragma unroll
        for (int j = 0; j < 8; ++j) {
            const int p = 8 * q + j;                  // k position (pi-order)
            const int u = 16 * (p & 1) + (p >> 1);    // unit index
            const float ws = kk * W_hh[r * H + u];
            const unsigned short whi = f2bf(ws);
            Bh[d][j] = (short)whi;
            Bl[d][j] = (short)f2bf(ws - bf2f(whi));
            if (q == 3) {
                Bx[d][j] = 0;                          // zero k-quad
            } else {
                const float wsx = kk * W_ih[r * IN_D + j];
                const unsigned short xwh = f2bf(wsx);
                // q=0,1 multiply x_hi/x_lo by W_hi; q=2 multiplies x_hi by W_lo
                Bx[d][j] = (q == 2) ? (short)f2bf(wsx - bf2f(xwh)) : (short)xwh;
            }
        }
        bias[d] = kk * (b_ih[r] + b_hh[r]);
    }
    const f32x4 biasv0 = { bias[0], bias[0], bias[0], bias[0] };
    const f32x4 biasv1 = { bias[1], bias[1], bias[1], bias[1] };

    // per-lane x A-frag offset: q0->xh, q1->xl, q2->xh (again), q3->zeros
    const int xoff = (q == 2) ? 0 : ((q == 3) ? 16 : 8 * q);

    // ---- x chunk machinery: thread -> (batch xb, step-in-chunk xs, half xhf) ----
    const int xb = tix >> 4, xs = (tix >> 1) & 7, xhf = tix & 1;
    const float* xbase = x + (size_t)(blockIdx.x * NBATCH + xb) * (size_t)(T_LEN * IN_D)
                           + xs * IN_D + 4 * xhf;
    auto ldchunk = [&](int ch) { return *(const float4*)(xbase + (size_t)ch * 8 * IN_D); };
    auto stage = [&](float4 v) {
        const unsigned h0 = cvt_pk_bf16(v.x, v.y);
        const unsigned h1 = cvt_pk_bf16(v.z, v.w);
        const unsigned l0 = cvt_pk_bf16(v.x - ubits(h0 << 16), v.y - ubits(h0 & 0xffff0000u));
        const unsigned l1 = cvt_pk_bf16(v.z - ubits(h1 << 16), v.w - ubits(h1 & 0xffff0000u));
        *(uint2*)&xstg[xs][xb][4 * xhf]     = make_uint2(h0, h1);
        *(uint2*)&xstg[xs][xb][8 + 4 * xhf] = make_uint2(l0, l1);
    };

    // ---- init: zero h and xstg (zero-quad region persists), stage chunk 0 ----
    for (int i = tix; i < NBATCH * 48 / 2; i += NT) {
        ((unsigned*)hhi)[i] = 0u;
        ((unsigned*)hlo)[i] = 0u;
    }
    for (int i = tix; i < 8 * 17 * 24 / 2; i += NT) ((unsigned*)xstg)[i] = 0u;
    __syncthreads();
    stage(ldchunk(0));
    float4 xbuf = ldchunk(1);
    __syncthreads();

    // ---- XC[s][d]: x-contribution + bias for the current chunk (64 VGPRs) ----
    f32x4 XC[8][2];
#define REFILL(j) do { \
        const bf16x8 Ax_ = *(const bf16x8*)&xstg[(j)][cc][xoff]; \
        XC[(j)][0] = __builtin_amdgcn_mfma_f32_16x16x32_bf16(Ax_, Bx[0], biasv0, 0, 0, 0); \
        XC[(j)][1] = __builtin_amdgcn_mfma_f32_16x16x32_bf16(Ax_, Bx[1], biasv1, 0, 0, 0); \
    } while (0)
    #pragma unroll
    for (int s = 0; s < 8; ++s) REFILL(s);

    const int m = tix >> 4, u0 = tix & 15;
    const float wfc0 = W_fc[u0], wfc1 = W_fc[u0 + 16];
    float cs0 = 0.f, cs1 = 0.f, h0f = 0.f, h1f = 0.f;

    for (int blk = 0; blk < NCHUNK; ++blk) {
        #pragma unroll
        for (int s = 0; s < 8; ++s) {
            // ---- h A-frags + 6 MFMAs (acc starts at precomputed XC) ----
            const bf16x8 A0 = *(const bf16x8*)&hhi[cc][8 * q];
            const bf16x8 A2 = *(const bf16x8*)&hlo[cc][8 * q];
            f32x4 C2[2];
            #pragma unroll
            for (int d = 0; d < 2; ++d) {
                const f32x4 z = { 0.f, 0.f, 0.f, 0.f };
                f32x4 a1 = __builtin_amdgcn_mfma_f32_16x16x32_bf16(A0, Bh[d], XC[s][d], 0, 0, 0);
                f32x4 a2 = __builtin_amdgcn_mfma_f32_16x16x32_bf16(A2, Bh[d], z, 0, 0, 0);
                a2 = __builtin_amdgcn_mfma_f32_16x16x32_bf16(A0, Bl[d], a2, 0, 0, 0);
                C2[d] = a1 + a2;
            }

            // ---- stage next chunk early (s==0): lands before refills need it ----
            if (s == 0) {
                stage(xbuf);
                int nc = blk + 2;
                if (nc > NCHUNK - 1) nc = NCHUNK - 1;
                xbuf = ldchunk(nc);
            }

            // ---- activation (kk pre-folded) -> pi-paired b64 G writes ----
            #pragma unroll
            for (int rg = 0; rg < 4; ++rg) {
                f32x2 pr;
                pr[0] = aa + bb * frcp(1.f + fexp2(C2[0][rg]));
                pr[1] = aa + bb * frcp(1.f + fexp2(C2[1][rg]));
                *(f32x2*)&G[w][4 * q + rg][2 * cc] = pr;
            }

            // ---- spread next-chunk XC refill: 2 MFMAs/step, off critical path ----
            if (s >= 1) REFILL(s - 1);
            if (s == 7) REFILL(7);

            WG_BARRIER();

            // ---- non-redundant c/h update: 2 cells/thread, exp2-domain c ----
            {
                const f32x2 gi = *(const f32x2*)&G[0][m][2 * u0];
                const f32x2 gf = *(const f32x2*)&G[1][m][2 * u0];
                const f32x2 gg = *(const f32x2*)&G[2][m][2 * u0];
                const f32x2 go = *(const f32x2*)&G[3][m][2 * u0];
                cs0 = gf[0] * cs0 + gi[0] * gg[0];     // cs = 2L*c
                cs1 = gf[1] * cs1 + gi[1] * gg[1];
                const float r0 = frcp(1.f + fexp2(cs0));
                const float r1 = frcp(1.f + fexp2(cs1));
                h0f = go[0] - 2.f * go[0] * r0;        // o * tanh(c)
                h1f = go[1] - 2.f * go[1] * r1;
                const unsigned hw = cvt_pk_bf16(h0f, h1f);        // pi: 2u0, 2u0+1
                const unsigned lw = cvt_pk_bf16(h0f - ubits(hw << 16),
                                                h1f - ubits(hw & 0xffff0000u));
                *(unsigned*)&hhi[m][2 * u0] = hw;
                *(unsigned*)&hlo[m][2 * u0] = lw;
            }

            WG_BARRIER();
        }
    }
#undef REFILL

    // ---- epilogue: out[b] = h_n . W_fc + b_fc (fp32 h, shfl reduce over u0) ----
    float sacc = h0f * wfc0 + h1f * wfc1;
    sacc += __shfl_xor(sacc, 1);
    sacc += __shfl_xor(sacc, 2);
    sacc += __shfl_xor(sacc, 4);
    sacc += __shfl_xor(sacc, 8);
    if (u0 == 0) out[blockIdx.x * NBATCH + m] = sacc + b_fc[0];
}

extern "C" void kernel_launch(void* const* d_in, const int* in_sizes, int n_in,
                              void* d_out, int out_size, void* d_ws, size_t ws_size,
                              hipStream_t stream) {
    const float* x    = (const float*)d_in[0];
    const float* W_ih = (const float*)d_in[1];
    const float* W_hh = (const float*)d_in[2];
    const float* b_ih = (const float*)d_in[3];
    const float* b_hh = (const float*)d_in[4];
    const float* W_fc = (const float*)d_in[5];
    const float* b_fc = (const float*)d_in[6];
    float* out = (float*)d_out;
    const int Bn = in_sizes[0] / (T_LEN * IN_D);   // 8192
    lstm_mfma4<<<dim3(Bn / NBATCH), dim3(NT), 0, stream>>>(
        x, W_ih, W_hh, b_ih, b_hh, W_fc, b_fc, out);
}

// Round 3
// 447.018 us; speedup vs baseline: 1.2419x; 1.0614x over previous
//
#include <hip/hip_runtime.h>
#include <cstddef>

#define T_LEN 512
#define IN_D 8
#define H 32
#define NBATCH 16        // batches per WG (MFMA M)
#define NT 512           // 8 waves: wave w owns tile (gate g=w>>1, half d=w&1)
#define NCHUNK (T_LEN / 8)
#define LOG2E 1.44269504088896341f
#define GP 36            // G row pad (words): 144q%32=16 -> writes exact 2-way

typedef __attribute__((ext_vector_type(8))) short bf16x8;
typedef __attribute__((ext_vector_type(4))) float f32x4;

__device__ __forceinline__ float fexp2(float v) { return __builtin_amdgcn_exp2f(v); }
__device__ __forceinline__ float frcp(float v)  { return __builtin_amdgcn_rcpf(v); }
__device__ __forceinline__ unsigned short f2bf(float f) {   // RNE fp32->bf16 (setup only)
    unsigned u = __builtin_bit_cast(unsigned, f);
    u += 0x7FFF + ((u >> 16) & 1);
    return (unsigned short)(u >> 16);
}
__device__ __forceinline__ float bf2f(unsigned short b) {
    unsigned u = ((unsigned)b) << 16;
    return __builtin_bit_cast(float, u);
}
__device__ __forceinline__ float ubits(unsigned u) { return __builtin_bit_cast(float, u); }
// packed RNE fp32x2 -> bf16x2 (arg0 -> low16, arg1 -> high16)
__device__ __forceinline__ unsigned cvt_pk_bf16(float lo, float hi) {
    unsigned r;
    asm("v_cvt_pk_bf16_f32 %0, %1, %2" : "=v"(r) : "v"(lo), "v"(hi));
    return r;
}

// LDS-only barrier: no vmcnt drain (global x-chunk loads stay in flight).
#define WG_BARRIER() asm volatile("s_waitcnt lgkmcnt(0)\n\ts_barrier" ::: "memory")

// R2 structure (XC-hoisted x contribution, 2 barriers, non-redundant c/h) but
// re-partitioned over 8 waves: wave w owns ONE 16x16 tile (gate w>>1, half w&1)
// -> 3 recurrence MFMAs + 1 XC refill + 4 activation values per wave per step.
// Per-wave issue halves vs R2; 4 waves/SIMD (was 2) fill the latency holes of
// this latency-bound serial recurrence. G[4][16][36] unit-major: activation
// writes exact 2-way banks, c/h reads exact 2-way banks. h written as paired
// b32 (shfl_xor(16) partner) to keep pi-layout and <=2-way banks.
__global__ void __launch_bounds__(NT, 4) lstm_mfma4(
    const float* __restrict__ x, const float* __restrict__ W_ih,
    const float* __restrict__ W_hh, const float* __restrict__ b_ih,
    const float* __restrict__ b_hh, const float* __restrict__ W_fc,
    const float* __restrict__ b_fc, float* __restrict__ out)
{
    __shared__ __align__(16) float G[4][NBATCH][GP];           // 9216 B, col = unit u
    __shared__ __align__(16) unsigned short hhi[NBATCH][48];   // 1536 B, pi-order k
    __shared__ __align__(16) unsigned short hlo[NBATCH][48];   // 1536 B
    __shared__ __align__(16) unsigned short xstg[8][17][24];   // 6528 B; cols 16-23 stay zero

    const int tix  = threadIdx.x;
    const int w    = tix >> 6;
    const int g    = w >> 1;            // gate id (0=i,1=f,2=g,3=o)
    const int d    = w & 1;             // tile half
    const int lane = tix & 63;
    const int q    = lane >> 4;         // k-quad (A/B) / row-group (C)
    const int cc   = lane & 15;         // A row (batch) / B col (unit-in-tile)

    const float kk = (g == 2) ? 2.f * LOG2E : -LOG2E;
    const float aa = (g == 2) ? 2.f * LOG2E : 0.f;     // g stored as 2L*tanh(g)
    const float bb = (g == 2) ? -4.f * LOG2E : 1.f;

    // ---- static B fragments for tile (g,d) (premultiplied by kk) ----
    bf16x8 Bh, Bl, Bx;
    const int r = 16 * (2 * g + d) + cc;              // global gate-row
    #pragma unroll
    for (int j = 0; j < 8; ++j) {
        const int p = 8 * q + j;                      // k position (pi-order)
        const int u = 16 * (p & 1) + (p >> 1);        // unit index
        const float ws = kk * W_hh[r * H + u];
        const unsigned short whi = f2bf(ws);
        Bh[j] = (short)whi;
        Bl[j] = (short)f2bf(ws - bf2f(whi));
        if (q == 3) {
            Bx[j] = 0;                                 // zero k-quad
        } else {
            const float wsx = kk * W_ih[r * IN_D + j];
            const unsigned short xwh = f2bf(wsx);
            // q=0,1 multiply x_hi/x_lo by W_hi; q=2 multiplies x_hi by W_lo
            Bx[j] = (q == 2) ? (short)f2bf(wsx - bf2f(xwh)) : (short)xwh;
        }
    }
    const float bias = kk * (b_ih[r] + b_hh[r]);
    const f32x4 biasv = { bias, bias, bias, bias };

    // per-lane x A-frag offset: q0->xh, q1->xl, q2->xh (again), q3->zeros
    const int xoff = (q == 2) ? 0 : ((q == 3) ? 16 : 8 * q);

    // ---- x chunk machinery (first 256 threads): (batch xb, step xs, half xhf) ----
    const int xb = (tix >> 4) & 15, xs = (tix >> 1) & 7, xhf = tix & 1;
    const bool stager = (tix < 256);
    const float* xbase = x + (size_t)(blockIdx.x * NBATCH + xb) * (size_t)(T_LEN * IN_D)
                           + xs * IN_D + 4 * xhf;
    auto ldchunk = [&](int ch) { return *(const float4*)(xbase + (size_t)ch * 8 * IN_D); };
    auto stage = [&](float4 v) {
        const unsigned h0 = cvt_pk_bf16(v.x, v.y);
        const unsigned h1 = cvt_pk_bf16(v.z, v.w);
        const unsigned l0 = cvt_pk_bf16(v.x - ubits(h0 << 16), v.y - ubits(h0 & 0xffff0000u));
        const unsigned l1 = cvt_pk_bf16(v.z - ubits(h1 << 16), v.w - ubits(h1 & 0xffff0000u));
        *(uint2*)&xstg[xs][xb][4 * xhf]     = make_uint2(h0, h1);
        *(uint2*)&xstg[xs][xb][8 + 4 * xhf] = make_uint2(l0, l1);
    };

    // ---- init: zero h and xstg (zero regions persist), stage chunk 0 ----
    for (int i = tix; i < NBATCH * 48 / 2; i += NT) {
        ((unsigned*)hhi)[i] = 0u;
        ((unsigned*)hlo)[i] = 0u;
    }
    for (int i = tix; i < 8 * 17 * 24 / 2; i += NT) ((unsigned*)xstg)[i] = 0u;
    __syncthreads();
    float4 xbuf = {0.f, 0.f, 0.f, 0.f};
    if (stager) {
        stage(ldchunk(0));
        xbuf = ldchunk(1);
    }
    __syncthreads();

    // ---- XC[s]: x-contribution + bias for this wave's tile (32 VGPRs) ----
    f32x4 XC[8];
#define REFILL(j) do { \
        const bf16x8 Ax_ = *(const bf16x8*)&xstg[(j)][cc][xoff]; \
        XC[(j)] = __builtin_amdgcn_mfma_f32_16x16x32_bf16(Ax_, Bx, biasv, 0, 0, 0); \
    } while (0)
    #pragma unroll
    for (int s = 0; s < 8; ++s) REFILL(s);

    // c/h ownership: 1 cell per thread: batch m, unit u
    const int m = tix >> 5, u = tix & 31;
    const float wfc = W_fc[u];
    float cs = 0.f, hf = 0.f;

    for (int blk = 0; blk < NCHUNK; ++blk) {
        #pragma unroll
        for (int s = 0; s < 8; ++s) {
            // ---- h A-frags + 3 MFMAs (acc starts at precomputed XC) ----
            const bf16x8 A0 = *(const bf16x8*)&hhi[cc][8 * q];
            const bf16x8 A2 = *(const bf16x8*)&hlo[cc][8 * q];
            const f32x4 z = { 0.f, 0.f, 0.f, 0.f };
            f32x4 a1 = __builtin_amdgcn_mfma_f32_16x16x32_bf16(A0, Bh, XC[s], 0, 0, 0);
            f32x4 a2 = __builtin_amdgcn_mfma_f32_16x16x32_bf16(A2, Bh, z, 0, 0, 0);
            a2 = __builtin_amdgcn_mfma_f32_16x16x32_bf16(A0, Bl, a2, 0, 0, 0);
            const f32x4 C = a1 + a2;

            // ---- stage next chunk early (s==0): consumed by refills from s==1 ----
            if (s == 0 && stager) {
                stage(xbuf);
                int nc = blk + 2;
                if (nc > NCHUNK - 1) nc = NCHUNK - 1;
                xbuf = ldchunk(nc);
            }

            // ---- activation (kk pre-folded) -> unit-major b32 G writes ----
            #pragma unroll
            for (int rg = 0; rg < 4; ++rg)
                G[g][4 * q + rg][cc + 16 * d] = aa + bb * frcp(1.f + fexp2(C[rg]));

            // ---- spread next-chunk XC refill: 1 MFMA/step, off critical path ----
            if (s >= 1) REFILL(s - 1);
            if (s == 7) REFILL(7);

            WG_BARRIER();

            // ---- non-redundant c/h update: 1 cell/thread, exp2-domain c ----
            {
                const float gi = G[0][m][u];
                const float gf = G[1][m][u];
                const float gg = G[2][m][u];
                const float go = G[3][m][u];
                cs = gf * cs + gi * gg;               // cs = 2L*c
                const float rr = frcp(1.f + fexp2(cs));
                hf = go - 2.f * go * rr;              // o * tanh(c)
                // pair (u, u+16) -> pi cols (2u', 2u'+1): partner via shfl
                const float hp = __shfl_xor(hf, 16);
                if ((tix & 16) == 0) {
                    const unsigned hw = cvt_pk_bf16(hf, hp);
                    const unsigned lw = cvt_pk_bf16(hf - ubits(hw << 16),
                                                    hp - ubits(hw & 0xffff0000u));
                    *(unsigned*)&hhi[m][2 * (u & 15)] = hw;
                    *(unsigned*)&hlo[m][2 * (u & 15)] = lw;
                }
            }

            WG_BARRIER();
        }
    }
#undef REFILL

    // ---- epilogue: out[b] = h_n . W_fc + b_fc (fp32 h, shfl reduce over u) ----
    float sacc = hf * wfc;
    sacc += __shfl_xor(sacc, 1);
    sacc += __shfl_xor(sacc, 2);
    sacc += __shfl_xor(sacc, 4);
    sacc += __shfl_xor(sacc, 8);
    sacc += __shfl_xor(sacc, 16);
    if ((tix & 31) == 0) out[blockIdx.x * NBATCH + m] = sacc + b_fc[0];
}

extern "C" void kernel_launch(void* const* d_in, const int* in_sizes, int n_in,
                              void* d_out, int out_size, void* d_ws, size_t ws_size,
                              hipStream_t stream) {
    const float* x    = (const float*)d_in[0];
    const float* W_ih = (const float*)d_in[1];
    const float* W_hh = (const float*)d_in[2];
    const float* b_ih = (const float*)d_in[3];
    const float* b_hh = (const float*)d_in[4];
    const float* W_fc = (const float*)d_in[5];
    const float* b_fc = (const float*)d_in[6];
    float* out = (float*)d_out;
    const int Bn = in_sizes[0] / (T_LEN * IN_D);   // 8192
    lstm_mfma4<<<dim3(Bn / NBATCH), dim3(NT), 0, stream>>>(
        x, W_ih, W_hh, b_ih, b_hh, W_fc, b_fc, out);
}